// Round 2
// baseline (156.762 us; speedup 1.0000x reference)
//
#include <hip/hip_runtime.h>
#include <math.h>

#define NS 4096
#define NT 4096
#define RPB 8                       // rows computed per block (reads RPB+2 -> 1.25x amp)
#define CCH 1024                    // columns per block
#define CPT 4                       // columns per thread (256 threads * 4 = 1024)
#define NRG (NS / RPB)              // 512 row groups
#define NCC (NT / CCH)              // 4 column chunks
#define NBLK (NRG * NCC)            // 2048 blocks = 8192 waves = 100% wave capacity

__device__ __forceinline__ double block_reduce(double v, int tid) {
    #pragma unroll
    for (int off = 32; off > 0; off >>= 1)
        v += __shfl_down(v, off, 64);
    __shared__ double lds[4];
    const int lane = tid & 63, wv = tid >> 6;
    if (lane == 0) lds[wv] = v;
    __syncthreads();
    return lds[0] + lds[1] + lds[2] + lds[3];   // valid in all threads
}

// Per-row stretch metrics, computed ONCE per row (was: every thread, every row,
// in f64 + a divide -> dominated VALUBusy). Bit-exact: identical op sequence.
__global__ __launch_bounds__(256) void bs_rows(float4* __restrict__ t0,
                                               float4* __restrict__ t1,
                                               double C1, double C2) {
    const int r = blockIdx.x * 256 + threadIdx.x;
    if (r >= NS) return;
    const double DU = 1.0 / (double)(NS - 1);
    const double dL = C2 - C1;
    const double u   = (double)r * DU;
    const double L   = C2 * u + C1 * (1.0 - u);
    const double S   = 100.0 + 30.0 * (L * L * L / 6.0 + L);
    const double dS  = 30.0 * dL * (0.5 * L * L + 1.0);
    const double d2S = 30.0 * dL * dL * L;
    const float Sn   = (float)(S   / 300.0);
    const float Sun  = (float)(dS  / 300.0);
    const float Suun = (float)(d2S / 300.0);
    const float invSun  = 1.0f / Sun;
    const float invSun3 = invSun * invSun * invSun;
    t0[r] = make_float4(Sn * Sn, 2.5f * Sn, Sun, Suun);      // {Sn2, ASn, Sun, Suun}
    t1[r] = make_float4(invSun, invSun3, (float)u, 0.0f);    // {invSun, invSun3, u}
}

// Each block: 8 rows x 1024 cols, rolling 3-row register window + 1-row-ahead
// prefetch (d). Reads 10 rows to compute 8 (1.25x amp). Thread t owns 4 cols.
__global__ __launch_bounds__(256, 8) void bs_main(const float* __restrict__ V,
                                                  const float4* __restrict__ t0,
                                                  const float4* __restrict__ t1,
                                                  double* __restrict__ part,
                                                  unsigned* __restrict__ cnt,
                                                  float* __restrict__ out) {
    const int tid = threadIdx.x;
    const int rg  = blockIdx.x >> 2;            // row group    (0..511)
    const int cc  = blockIdx.x & 3;             // column chunk (0..3)
    const int r0  = rg * RPB;
    const int j0  = cc * CCH + tid * CPT;

    const float INV2DU = 2047.5f;      // 1/(2*DU)
    const float INVDU2 = 16769025.0f;  // 1/DU^2 = 4095^2
    const float INV2DT = 102375.0f;    // 1/(2*DT_NORM)
    const float AL     = 2.5f;         // 2r/sigma^2

    const float* rowp = V + j0;
    const int rm = (r0 > 0) ? r0 - 1 : 0;
    float4 a  = *(const float4*)(rowp + (size_t)rm * NT);
    float4 b  = *(const float4*)(rowp + (size_t)r0 * NT);
    float4 c  = *(const float4*)(rowp + (size_t)(r0 + 1) * NT);
    float4 m0 = t0[r0];                         // uniform addr -> scalar cache
    float4 m1 = t1[r0];

    double pde = 0.0, bc = 0.0, tc = 0.0;

    #pragma unroll
    for (int rr = 0; rr < RPB; ++rr) {
        const int r = r0 + rr;

        // ---- prefetch next row + next row constants (load-use dist = 1 row) ----
        float4 d, n0, n1;
        if (rr < RPB - 1) {
            int rpre = r + 2; if (rpre > NS - 1) rpre = NS - 1;
            d  = *(const float4*)(rowp + (size_t)rpre * NT);
            n0 = t0[r + 1];
            n1 = t1[r + 1];
        }

        if (r >= 1 && r <= NS - 2) {
            // horizontal edge neighbors of this thread's 4-col strip (L1 hits)
            const float lf = (j0 > 0)        ? V[(size_t)r * NT + j0 - 1]   : 0.0f;
            const float rt = (j0 + CPT < NT) ? V[(size_t)r * NT + j0 + CPT] : 0.0f;

            const float aa[4] = {a.x, a.y, a.z, a.w};
            const float bb[4] = {b.x, b.y, b.z, b.w};
            const float cv[4] = {c.x, c.y, c.z, c.w};

            float pf = 0.0f;   // f32 row partial; /n_int at the end -> negligible
            #pragma unroll
            for (int k = 0; k < CPT; ++k) {
                const int j = j0 + k;
                if (j >= 1 && j <= NT - 2) {
                    const float cm = (k == 0)       ? lf : bb[k - 1];
                    const float cp = (k == CPT - 1) ? rt : bb[k + 1];
                    const float Vu  = (cv[k] - aa[k]) * INV2DU;
                    const float Vuu = (cv[k] - 2.0f * bb[k] + aa[k]) * INVDU2;
                    const float Vt  = (cp - cm) * INV2DT;
                    const float VS  = Vu * m1.x;                        // * invSun
                    float VSS = (Vuu * m0.z - Vu * m0.w) * m1.y;        // (Vuu*Sun - Vu*Suun)*invSun3
                    VSS = fminf(fmaxf(VSS, -100.0f), 100.0f);
                    const float res = Vt - m0.x * VSS - m0.y * VS + AL * bb[k];
                    pf += res * res;
                }
            }
            pde += (double)pf;
        }

        if (r == NS - 1) {
            // far-field BC at S=Smax over this thread's 4 columns
            const float bb[4] = {b.x, b.y, b.z, b.w};
            #pragma unroll
            for (int k = 0; k < CPT; ++k) {
                const float t   = (float)(j0 + k) * (1.0f / (float)(NT - 1));
                const float tgt = 1.0f - (100.0f / 300.0f) * expf(-0.05f * (1.0f - t));
                const float dd  = bb[k] - tgt;
                bc += (double)(dd * dd);
            }
        }

        if (j0 + CPT == NT) {
            // terminal condition element V[r, NT-1] == b.w
            const float ui = m1.z;
            const float x  = 50.0f * (ui - 100.0f / 300.0f);
            const float sp = fmaxf(x, 0.0f) + log1pf(expf(-fabsf(x)));
            const float payoff = sp * (1.0f / 50.0f);
            const float dd = b.w - payoff;
            const float ad = fabsf(dd);
            tc += (double)((ad < 0.01f) ? 0.5f * dd * dd : 0.01f * (ad - 0.005f));
        }

        // roll the window (register renames after full unroll)
        if (rr < RPB - 1) { a = b; b = c; c = d; m0 = n0; m1 = n1; }
    }

    const double n_int = (double)(NS - 2) * (double)(NT - 2);
    double contrib = pde * (1.0 / n_int)
                   + bc  * (10.0 / (double)NT)
                   + tc  * (10.0 / (double)NS);

    contrib = block_reduce(contrib, tid);

    // ---- last-block-done cross-block reduction (no second big launch) ----
    __shared__ int amLast;
    if (tid == 0) {
        part[blockIdx.x] = contrib;
        __threadfence();                               // make part[] globally visible
        const unsigned old = atomicAdd(cnt, 1u);       // device-scope
        amLast = (old == (unsigned)(NBLK - 1));
    }
    __syncthreads();

    if (amLast) {
        double s = 0.0;
        for (int idx = tid; idx < NBLK; idx += 256)
            s += atomicAdd(&part[idx], 0.0);           // device-scope coherent read
        s = block_reduce(s, tid);
        if (tid == 0) out[0] = (float)s;
    }
}

// Host-side faithful port of CubicStretching._solve_depressed_cubic.
static double cubic_root_host(double Q) {
    const double p = 6.0;                 // CHI
    const double q = p * Q;               // CHI * Q
    const double sp = sqrt(p);
    double arg = fabs(q) / (2.0 * p * sp / (3.0 * sqrt(3.0)));
    if (arg < 1.0) arg = 1.0;
    const double c = 2.0 * sp * cosh(acosh(arg) / 3.0);
    return (q >= 0.0) ? -c : c;
}

extern "C" void kernel_launch(void* const* d_in, const int* in_sizes, int n_in,
                              void* d_out, int out_size, void* d_ws, size_t ws_size,
                              hipStream_t stream) {
    const float* V  = (const float*)d_in[0];
    float* out      = (float*)d_out;

    // workspace layout: part[NBLK] doubles | cnt | (32KB:) t0[NS] | t1[NS]
    double*   part = (double*)d_ws;
    unsigned* cnt  = (unsigned*)((char*)d_ws + NBLK * sizeof(double));
    float4*   t0   = (float4*)((char*)d_ws + 32768);
    float4*   t1   = (float4*)((char*)d_ws + 32768 + NS * sizeof(float4));

    const double C1 = cubic_root_host((100.0 - 0.0)   / 30.0);
    const double C2 = cubic_root_host((100.0 - 300.0) / 30.0);

    hipMemsetAsync(cnt, 0, sizeof(unsigned), stream);        // zero arrival counter
    bs_rows<<<(NS + 255) / 256, 256, 0, stream>>>(t0, t1, C1, C2);
    bs_main<<<NBLK, 256, 0, stream>>>(V, t0, t1, part, cnt, out);
}